// Round 8
// baseline (212.504 us; speedup 1.0000x reference)
//
#include <hip/hip_runtime.h>
#include <hip/hip_fp16.h>

#define IN_DIM 128
#define TWO_IN 256
#define CAP 192      // max in-degree capacity (Poisson mean 64 -> 192 is ~12 sigma)
#define NB 16        // nodes per block in k_gemmP
#define ONB 16       // nodes per block in k_out

// ---------- K_prep: W1eff[257][128] = [W1_top ; We@W1_bot ; be@W1_bot]; zero cnt ----------
__global__ void k_prep(const float* __restrict__ We, const float* __restrict__ be,
                       const float* __restrict__ W1, float* __restrict__ W1eff,
                       int* __restrict__ cnt, int n) {
    __shared__ float wes[8][IN_DIM];
    int tid = threadIdx.x;            // 128
    int r0 = blockIdx.x * 8;          // 16 blocks
    for (int i = blockIdx.x * 128 + tid; i < n; i += 16 * 128) cnt[i] = 0;
    for (int i = tid; i < 8 * IN_DIM; i += 128) {
        int m = i >> 7, c = i & 127;
        wes[m][c] = We[(r0 + m) * IN_DIM + c];
    }
    __syncthreads();
    float acc[8];
    #pragma unroll
    for (int m = 0; m < 8; ++m) acc[m] = 0.f;
    for (int c = 0; c < IN_DIM; ++c) {
        float w = W1[(IN_DIM + c) * IN_DIM + tid];
        #pragma unroll
        for (int m = 0; m < 8; ++m) acc[m] += wes[m][c] * w;
    }
    #pragma unroll
    for (int m = 0; m < 8; ++m) {
        W1eff[(IN_DIM + r0 + m) * IN_DIM + tid] = acc[m];
        W1eff[(r0 + m) * IN_DIM + tid] = W1[(r0 + m) * IN_DIM + tid];
    }
    if (blockIdx.x == 0) {
        float va = 0.f;
        for (int c = 0; c < IN_DIM; ++c) va += be[c] * W1[(IN_DIM + c) * IN_DIM + tid];
        W1eff[(size_t)TWO_IN * IN_DIM + tid] = va;   // row 256
    }
}

// ---------- K_fill: bucket CSR (one 8B scattered store per edge) ----------
__global__ void k_fill(const int* __restrict__ src, const int* __restrict__ dst,
                       int* __restrict__ cnt, int2* __restrict__ slots, int E) {
    int e = blockIdx.x * blockDim.x + threadIdx.x;
    if (e < E) {
        int d = dst[e];
        int pos = atomicAdd(&cnt[d], 1);
        slots[(size_t)d * CAP + pos] = make_int2(src[e], e);
    }
}

// ---------- K_agg: aggE[v] = sum edge_attr rows (dual-edge float4, 8 in flight/half) ----------
__global__ void __launch_bounds__(256)
k_agg(const float* __restrict__ edge_attr,
      const int2* __restrict__ slots,
      const int* __restrict__ cnt,
      float* __restrict__ aggE, int n) {
    int wave = (int)((blockIdx.x * blockDim.x + threadIdx.x) >> 6);
    int lane = threadIdx.x & 63;
    if (wave >= n) return;
    int c = cnt[wave];
    int half = lane >> 5, l = lane & 31;
    const float4* E4 = (const float4*)edge_attr;   // row = 32 float4
    float4 a0 = {0,0,0,0}, a1 = {0,0,0,0}, a2 = {0,0,0,0}, a3 = {0,0,0,0};
    float4 a4 = {0,0,0,0}, a5 = {0,0,0,0}, a6 = {0,0,0,0}, a7 = {0,0,0,0};
    size_t rb = (size_t)wave * CAP;
    for (int b = 0; b < c; b += 64) {
        int rem = min(64, c - b);
        int eid = (b + lane < c) ? slots[rb + b + lane].y : 0;
        int i = 0;
        for (; i + 15 < rem; i += 16) {
            int t0  = __builtin_amdgcn_readlane(eid, i + 0);
            int t1  = __builtin_amdgcn_readlane(eid, i + 1);
            int t2  = __builtin_amdgcn_readlane(eid, i + 2);
            int t3  = __builtin_amdgcn_readlane(eid, i + 3);
            int t4  = __builtin_amdgcn_readlane(eid, i + 4);
            int t5  = __builtin_amdgcn_readlane(eid, i + 5);
            int t6  = __builtin_amdgcn_readlane(eid, i + 6);
            int t7  = __builtin_amdgcn_readlane(eid, i + 7);
            int t8  = __builtin_amdgcn_readlane(eid, i + 8);
            int t9  = __builtin_amdgcn_readlane(eid, i + 9);
            int t10 = __builtin_amdgcn_readlane(eid, i + 10);
            int t11 = __builtin_amdgcn_readlane(eid, i + 11);
            int t12 = __builtin_amdgcn_readlane(eid, i + 12);
            int t13 = __builtin_amdgcn_readlane(eid, i + 13);
            int t14 = __builtin_amdgcn_readlane(eid, i + 14);
            int t15 = __builtin_amdgcn_readlane(eid, i + 15);
            int e0 = half ? t1  : t0;
            int e1 = half ? t3  : t2;
            int e2 = half ? t5  : t4;
            int e3 = half ? t7  : t6;
            int e4 = half ? t9  : t8;
            int e5 = half ? t11 : t10;
            int e6 = half ? t13 : t12;
            int e7 = half ? t15 : t14;
            float4 v0 = E4[(size_t)e0 * 32 + l];
            float4 v1 = E4[(size_t)e1 * 32 + l];
            float4 v2 = E4[(size_t)e2 * 32 + l];
            float4 v3 = E4[(size_t)e3 * 32 + l];
            float4 v4 = E4[(size_t)e4 * 32 + l];
            float4 v5 = E4[(size_t)e5 * 32 + l];
            float4 v6 = E4[(size_t)e6 * 32 + l];
            float4 v7 = E4[(size_t)e7 * 32 + l];
            a0.x += v0.x; a0.y += v0.y; a0.z += v0.z; a0.w += v0.w;
            a1.x += v1.x; a1.y += v1.y; a1.z += v1.z; a1.w += v1.w;
            a2.x += v2.x; a2.y += v2.y; a2.z += v2.z; a2.w += v2.w;
            a3.x += v3.x; a3.y += v3.y; a3.z += v3.z; a3.w += v3.w;
            a4.x += v4.x; a4.y += v4.y; a4.z += v4.z; a4.w += v4.w;
            a5.x += v5.x; a5.y += v5.y; a5.z += v5.z; a5.w += v5.w;
            a6.x += v6.x; a6.y += v6.y; a6.z += v6.z; a6.w += v6.w;
            a7.x += v7.x; a7.y += v7.y; a7.z += v7.z; a7.w += v7.w;
        }
        for (; i + 1 < rem; i += 2) {
            int ta = __builtin_amdgcn_readlane(eid, i);
            int tb = __builtin_amdgcn_readlane(eid, i + 1);
            int e0 = half ? tb : ta;
            float4 v0 = E4[(size_t)e0 * 32 + l];
            a0.x += v0.x; a0.y += v0.y; a0.z += v0.z; a0.w += v0.w;
        }
        if (i < rem) {
            int ta = __builtin_amdgcn_readlane(eid, i);
            if (half == 0) {
                float4 v0 = E4[(size_t)ta * 32 + l];
                a0.x += v0.x; a0.y += v0.y; a0.z += v0.z; a0.w += v0.w;
            }
        }
    }
    float4 t;
    t.x = ((a0.x + a1.x) + (a2.x + a3.x)) + ((a4.x + a5.x) + (a6.x + a7.x));
    t.y = ((a0.y + a1.y) + (a2.y + a3.y)) + ((a4.y + a5.y) + (a6.y + a7.y));
    t.z = ((a0.z + a1.z) + (a2.z + a3.z)) + ((a4.z + a5.z) + (a6.z + a7.z));
    t.w = ((a0.w + a1.w) + (a2.w + a3.w)) + ((a4.w + a5.w) + (a6.w + a7.w));
    t.x += __shfl_xor(t.x, 32);
    t.y += __shfl_xor(t.y, 32);
    t.z += __shfl_xor(t.z, 32);
    t.w += __shfl_xor(t.w, 32);
    if (half == 0) ((float4*)aggE)[(size_t)wave * 32 + l] = t;
}

// ---------- K_P: P = [x | aggE | cnt] @ W1eff  (fp16 out, no b1) ----------
__global__ void k_gemmP(const float* __restrict__ x, const float* __restrict__ aggE,
                        const int* __restrict__ cnt, const float* __restrict__ W1eff,
                        __half* __restrict__ P, int n) {
    __shared__ float hs[NB][TWO_IN];
    __shared__ float degs[NB];
    int tid = threadIdx.x;  // 128
    int base = blockIdx.x * NB;
    const float4* X4 = (const float4*)(x + (size_t)base * IN_DIM);
    const float4* A4 = (const float4*)(aggE + (size_t)base * IN_DIM);
    int tot4 = NB * IN_DIM / 4;                    // 512 per half
    for (int i = tid; i < tot4; i += 128) {
        int m = i >> 5, c = i & 31;                // IN_DIM/4 = 32
        float4 vx = {0.f,0.f,0.f,0.f}, va = {0.f,0.f,0.f,0.f};
        if (base + m < n) { vx = X4[i]; va = A4[i]; }
        ((float4*)&hs[m][0])[c] = vx;
        ((float4*)&hs[m][IN_DIM])[c] = va;
    }
    if (tid < NB) degs[tid] = (base + tid < n) ? (float)cnt[base + tid] : 0.f;
    __syncthreads();
    float acc[NB];
    #pragma unroll
    for (int m = 0; m < NB; ++m) acc[m] = 0.f;
    for (int k = 0; k < TWO_IN; ++k) {
        float w = W1eff[k * IN_DIM + tid];
        #pragma unroll
        for (int m = 0; m < NB; ++m) acc[m] += hs[m][k] * w;
    }
    float w256 = W1eff[(size_t)TWO_IN * IN_DIM + tid];
    #pragma unroll
    for (int m = 0; m < NB; ++m) {
        int node = base + m;
        if (node < n)
            P[(size_t)node * IN_DIM + tid] = __float2half(acc[m] + degs[m] * w256);
    }
}

// ---------- K_out: acc = P[v] + sum_in P[src]; out = relu(acc+b1) @ W2 + b2 ----------
__global__ void __launch_bounds__(512)
k_out(const __half* __restrict__ P, const int2* __restrict__ slots,
      const int* __restrict__ cnt,
      const float* __restrict__ b1, const float* __restrict__ W2,
      const float* __restrict__ b2,
      float* __restrict__ out, int n) {
    __shared__ float hs[ONB][IN_DIM];
    __shared__ float sb1v[IN_DIM];
    int tid = threadIdx.x;           // 512 (8 waves)
    int wid = tid >> 6, lane = tid & 63;
    int half = lane >> 5, l = lane & 31;
    int base = blockIdx.x * ONB;
    if (tid < IN_DIM) sb1v[tid] = b1[tid];
    const uint2* P8 = (const uint2*)P;   // row = 32 uint2 (8B = 4 halves)
    #pragma unroll
    for (int j = 0; j < 2; ++j) {
        int m = wid * 2 + j;
        int v = base + m;
        float4 r = {0.f, 0.f, 0.f, 0.f};
        if (v < n) {
            int c = cnt[v];
            size_t rb = (size_t)v * CAP;
            float4 a0 = {0,0,0,0}, a1 = {0,0,0,0}, a2 = {0,0,0,0}, a3 = {0,0,0,0};
            float4 a4 = {0,0,0,0}, a5 = {0,0,0,0}, a6 = {0,0,0,0}, a7 = {0,0,0,0};
            for (int b = 0; b < c; b += 64) {
                int rem = min(64, c - b);
                int sid = (b + lane < c) ? slots[rb + b + lane].x : 0;
                int i = 0;
                for (; i + 15 < rem; i += 16) {
                    int t0  = __builtin_amdgcn_readlane(sid, i + 0);
                    int t1  = __builtin_amdgcn_readlane(sid, i + 1);
                    int t2  = __builtin_amdgcn_readlane(sid, i + 2);
                    int t3  = __builtin_amdgcn_readlane(sid, i + 3);
                    int t4  = __builtin_amdgcn_readlane(sid, i + 4);
                    int t5  = __builtin_amdgcn_readlane(sid, i + 5);
                    int t6  = __builtin_amdgcn_readlane(sid, i + 6);
                    int t7  = __builtin_amdgcn_readlane(sid, i + 7);
                    int t8  = __builtin_amdgcn_readlane(sid, i + 8);
                    int t9  = __builtin_amdgcn_readlane(sid, i + 9);
                    int t10 = __builtin_amdgcn_readlane(sid, i + 10);
                    int t11 = __builtin_amdgcn_readlane(sid, i + 11);
                    int t12 = __builtin_amdgcn_readlane(sid, i + 12);
                    int t13 = __builtin_amdgcn_readlane(sid, i + 13);
                    int t14 = __builtin_amdgcn_readlane(sid, i + 14);
                    int t15 = __builtin_amdgcn_readlane(sid, i + 15);
                    int s0 = half ? t1  : t0;
                    int s1 = half ? t3  : t2;
                    int s2 = half ? t5  : t4;
                    int s3 = half ? t7  : t6;
                    int s4 = half ? t9  : t8;
                    int s5 = half ? t11 : t10;
                    int s6 = half ? t13 : t12;
                    int s7 = half ? t15 : t14;
                    uint2 u0 = P8[(size_t)s0 * 32 + l];
                    uint2 u1 = P8[(size_t)s1 * 32 + l];
                    uint2 u2 = P8[(size_t)s2 * 32 + l];
                    uint2 u3 = P8[(size_t)s3 * 32 + l];
                    uint2 u4 = P8[(size_t)s4 * 32 + l];
                    uint2 u5 = P8[(size_t)s5 * 32 + l];
                    uint2 u6 = P8[(size_t)s6 * 32 + l];
                    uint2 u7 = P8[(size_t)s7 * 32 + l];
                    float2 lo, hi;
                    lo = __half22float2(*(const __half2*)&u0.x);
                    hi = __half22float2(*(const __half2*)&u0.y);
                    a0.x += lo.x; a0.y += lo.y; a0.z += hi.x; a0.w += hi.y;
                    lo = __half22float2(*(const __half2*)&u1.x);
                    hi = __half22float2(*(const __half2*)&u1.y);
                    a1.x += lo.x; a1.y += lo.y; a1.z += hi.x; a1.w += hi.y;
                    lo = __half22float2(*(const __half2*)&u2.x);
                    hi = __half22float2(*(const __half2*)&u2.y);
                    a2.x += lo.x; a2.y += lo.y; a2.z += hi.x; a2.w += hi.y;
                    lo = __half22float2(*(const __half2*)&u3.x);
                    hi = __half22float2(*(const __half2*)&u3.y);
                    a3.x += lo.x; a3.y += lo.y; a3.z += hi.x; a3.w += hi.y;
                    lo = __half22float2(*(const __half2*)&u4.x);
                    hi = __half22float2(*(const __half2*)&u4.y);
                    a4.x += lo.x; a4.y += lo.y; a4.z += hi.x; a4.w += hi.y;
                    lo = __half22float2(*(const __half2*)&u5.x);
                    hi = __half22float2(*(const __half2*)&u5.y);
                    a5.x += lo.x; a5.y += lo.y; a5.z += hi.x; a5.w += hi.y;
                    lo = __half22float2(*(const __half2*)&u6.x);
                    hi = __half22float2(*(const __half2*)&u6.y);
                    a6.x += lo.x; a6.y += lo.y; a6.z += hi.x; a6.w += hi.y;
                    lo = __half22float2(*(const __half2*)&u7.x);
                    hi = __half22float2(*(const __half2*)&u7.y);
                    a7.x += lo.x; a7.y += lo.y; a7.z += hi.x; a7.w += hi.y;
                }
                for (; i + 1 < rem; i += 2) {
                    int ta = __builtin_amdgcn_readlane(sid, i);
                    int tb = __builtin_amdgcn_readlane(sid, i + 1);
                    int s0 = half ? tb : ta;
                    uint2 u0 = P8[(size_t)s0 * 32 + l];
                    float2 lo = __half22float2(*(const __half2*)&u0.x);
                    float2 hi = __half22float2(*(const __half2*)&u0.y);
                    a0.x += lo.x; a0.y += lo.y; a0.z += hi.x; a0.w += hi.y;
                }
                if (i < rem) {
                    int ta = __builtin_amdgcn_readlane(sid, i);
                    if (half == 0) {
                        uint2 u0 = P8[(size_t)ta * 32 + l];
                        float2 lo = __half22float2(*(const __half2*)&u0.x);
                        float2 hi = __half22float2(*(const __half2*)&u0.y);
                        a0.x += lo.x; a0.y += lo.y; a0.z += hi.x; a0.w += hi.y;
                    }
                }
            }
            if (half == 0) {   // self term, once
                uint2 u0 = P8[(size_t)v * 32 + l];
                float2 lo = __half22float2(*(const __half2*)&u0.x);
                float2 hi = __half22float2(*(const __half2*)&u0.y);
                a0.x += lo.x; a0.y += lo.y; a0.z += hi.x; a0.w += hi.y;
            }
            r.x = ((a0.x + a1.x) + (a2.x + a3.x)) + ((a4.x + a5.x) + (a6.x + a7.x));
            r.y = ((a0.y + a1.y) + (a2.y + a3.y)) + ((a4.y + a5.y) + (a6.y + a7.y));
            r.z = ((a0.z + a1.z) + (a2.z + a3.z)) + ((a4.z + a5.z) + (a6.z + a7.z));
            r.w = ((a0.w + a1.w) + (a2.w + a3.w)) + ((a4.w + a5.w) + (a6.w + a7.w));
            r.x += __shfl_xor(r.x, 32);
            r.y += __shfl_xor(r.y, 32);
            r.z += __shfl_xor(r.z, 32);
            r.w += __shfl_xor(r.w, 32);
        }
        if (half == 0 && v < n) ((float4*)&hs[m][0])[l] = r;
    }
    __syncthreads();
    int col = tid & 127, grp = tid >> 7;     // grp = 0..3
    float acc[4] = {0.f, 0.f, 0.f, 0.f};
    for (int k = 0; k < IN_DIM; ++k) {
        float w = W2[k * IN_DIM + col];
        float bb = sb1v[k];
        #pragma unroll
        for (int j = 0; j < 4; ++j) {
            float t = hs[grp + 4 * j][k] + bb;
            acc[j] += (t > 0.f ? t : 0.f) * w;
        }
    }
    float b2v = b2[col];
    #pragma unroll
    for (int j = 0; j < 4; ++j) {
        int v = base + grp + 4 * j;
        if (v < n) out[(size_t)v * IN_DIM + col] = acc[j] + b2v;
    }
}

extern "C" void kernel_launch(void* const* d_in, const int* in_sizes, int n_in,
                              void* d_out, int out_size, void* d_ws, size_t ws_size,
                              hipStream_t stream) {
    const float* x         = (const float*)d_in[0];
    const int*   ei        = (const int*)d_in[1];
    const float* edge_attr = (const float*)d_in[2];
    const float* We        = (const float*)d_in[3];
    const float* be        = (const float*)d_in[4];
    const float* W1        = (const float*)d_in[5];
    const float* b1        = (const float*)d_in[6];
    const float* W2        = (const float*)d_in[7];
    const float* b2        = (const float*)d_in[8];
    float* out = (float*)d_out;

    int N = in_sizes[0] / IN_DIM;
    int E = in_sizes[1] / 2;
    const int* src = ei;
    const int* dst = ei + E;

    char* ws = (char*)d_ws;
    size_t o = 0;
    auto take = [&](size_t nbytes) -> void* {
        void* p = (void*)(ws + o);
        o += (nbytes + 255) & ~(size_t)255;
        return p;
    };
    int*    cnt   = (int*)take((size_t)N * 4);
    int2*   slots = (int2*)take(((size_t)N * CAP + 64) * 8);
    float*  aggE  = (float*)take((size_t)N * IN_DIM * 4);
    __half* P     = (__half*)take((size_t)N * IN_DIM * 2);
    float*  W1eff = (float*)take((size_t)(TWO_IN + 1) * IN_DIM * 4);
    (void)ws_size; (void)n_in; (void)out_size;

    int gE = (E + 255) / 256;
    int gW = (N * 64 + 255) / 256;       // one wave per node
    int gP = (N + NB - 1) / NB;
    int gO = (N + ONB - 1) / ONB;

    k_prep<<<16, 128, 0, stream>>>(We, be, W1, W1eff, cnt, N);
    k_fill<<<gE, 256, 0, stream>>>(src, dst, cnt, slots, E);
    k_agg<<<gW, 256, 0, stream>>>(edge_attr, slots, cnt, aggE, N);
    k_gemmP<<<gP, 128, 0, stream>>>(x, aggE, cnt, W1eff, P, N);
    k_out<<<gO, 512, 0, stream>>>(P, slots, cnt, b1, W2, b2, out, N);
}

// Round 9
// 185.005 us; speedup vs baseline: 1.1486x; 1.1486x over previous
//
#include <hip/hip_runtime.h>
#include <hip/hip_fp16.h>

#define IN_DIM 128
#define TWO_IN 256
#define CAP 192      // max in-degree capacity (Poisson mean 64 -> ~12 sigma margin)
#define ONB 16       // nodes per block in k_out

// ---------- K_prep: W1eff[257][128] = [W1_top ; We@W1_bot ; be@W1_bot]; zero cnt ----------
__global__ void k_prep(const float* __restrict__ We, const float* __restrict__ be,
                       const float* __restrict__ W1, float* __restrict__ W1eff,
                       int* __restrict__ cnt, int n) {
    __shared__ float wes[8][IN_DIM];
    int tid = threadIdx.x;            // 128
    int r0 = blockIdx.x * 8;          // 16 blocks
    for (int i = blockIdx.x * 128 + tid; i < n; i += 16 * 128) cnt[i] = 0;
    for (int i = tid; i < 8 * IN_DIM; i += 128) {
        int m = i >> 7, c = i & 127;
        wes[m][c] = We[(r0 + m) * IN_DIM + c];
    }
    __syncthreads();
    float acc[8];
    #pragma unroll
    for (int m = 0; m < 8; ++m) acc[m] = 0.f;
    for (int c = 0; c < IN_DIM; ++c) {
        float w = W1[(IN_DIM + c) * IN_DIM + tid];
        #pragma unroll
        for (int m = 0; m < 8; ++m) acc[m] += wes[m][c] * w;
    }
    #pragma unroll
    for (int m = 0; m < 8; ++m) {
        W1eff[(IN_DIM + r0 + m) * IN_DIM + tid] = acc[m];
        W1eff[(r0 + m) * IN_DIM + tid] = W1[(r0 + m) * IN_DIM + tid];
    }
    if (blockIdx.x == 0) {
        float va = 0.f;
        for (int c = 0; c < IN_DIM; ++c) va += be[c] * W1[(IN_DIM + c) * IN_DIM + tid];
        W1eff[(size_t)TWO_IN * IN_DIM + tid] = va;   // row 256
    }
}

// ---------- K_fill: bucket CSR (one 8B scattered store per edge) ----------
__global__ void k_fill(const int* __restrict__ src, const int* __restrict__ dst,
                       int* __restrict__ cnt, int2* __restrict__ slots, int E) {
    int e = blockIdx.x * blockDim.x + threadIdx.x;
    if (e < E) {
        int d = dst[e];
        int pos = atomicAdd(&cnt[d], 1);
        slots[(size_t)d * CAP + pos] = make_int2(src[e], e);
    }
}

// ---------- K_aggP: gather edge_attr rows -> aggE in LDS -> P = [x|aggE|deg]@W1eff (fp16) ----------
__global__ void __launch_bounds__(256)
k_aggP(const float* __restrict__ x, const float* __restrict__ edge_attr,
       const int2* __restrict__ slots, const int* __restrict__ cnt,
       const float* __restrict__ W1eff, __half* __restrict__ P, int n) {
    __shared__ float hs[4][TWO_IN];
    __shared__ float degs[4];
    int tid = threadIdx.x;          // 256 (4 waves, 1 node each)
    int wid = tid >> 6, lane = tid & 63;
    int half = lane >> 5, l = lane & 31;
    int v = blockIdx.x * 4 + wid;
    if (v < n) {
        int c = cnt[v];
        if (lane == 0) degs[wid] = (float)c;
        // x row -> hs[wid][0..127]
        float2 xv = ((const float2*)x)[(size_t)v * 64 + lane];
        ((float2*)&hs[wid][0])[lane] = xv;
        // gather + sum edge rows (dual-edge float4, 4 loads in flight per half-wave)
        const float4* E4 = (const float4*)edge_attr;   // row = 32 float4
        float4 a0 = {0,0,0,0}, a1 = {0,0,0,0}, a2 = {0,0,0,0}, a3 = {0,0,0,0};
        size_t rb = (size_t)v * CAP;
        for (int b = 0; b < c; b += 64) {
            int rem = min(64, c - b);
            int eid = (b + lane < c) ? slots[rb + b + lane].y : 0;
            int i = 0;
            for (; i + 7 < rem; i += 8) {
                int t0 = __builtin_amdgcn_readlane(eid, i + 0);
                int t1 = __builtin_amdgcn_readlane(eid, i + 1);
                int t2 = __builtin_amdgcn_readlane(eid, i + 2);
                int t3 = __builtin_amdgcn_readlane(eid, i + 3);
                int t4 = __builtin_amdgcn_readlane(eid, i + 4);
                int t5 = __builtin_amdgcn_readlane(eid, i + 5);
                int t6 = __builtin_amdgcn_readlane(eid, i + 6);
                int t7 = __builtin_amdgcn_readlane(eid, i + 7);
                int e0 = half ? t1 : t0;
                int e1 = half ? t3 : t2;
                int e2 = half ? t5 : t4;
                int e3 = half ? t7 : t6;
                float4 v0 = E4[(size_t)e0 * 32 + l];
                float4 v1 = E4[(size_t)e1 * 32 + l];
                float4 v2 = E4[(size_t)e2 * 32 + l];
                float4 v3 = E4[(size_t)e3 * 32 + l];
                a0.x += v0.x; a0.y += v0.y; a0.z += v0.z; a0.w += v0.w;
                a1.x += v1.x; a1.y += v1.y; a1.z += v1.z; a1.w += v1.w;
                a2.x += v2.x; a2.y += v2.y; a2.z += v2.z; a2.w += v2.w;
                a3.x += v3.x; a3.y += v3.y; a3.z += v3.z; a3.w += v3.w;
            }
            for (; i + 1 < rem; i += 2) {
                int ta = __builtin_amdgcn_readlane(eid, i);
                int tb = __builtin_amdgcn_readlane(eid, i + 1);
                int e0 = half ? tb : ta;
                float4 v0 = E4[(size_t)e0 * 32 + l];
                a0.x += v0.x; a0.y += v0.y; a0.z += v0.z; a0.w += v0.w;
            }
            if (i < rem) {
                int ta = __builtin_amdgcn_readlane(eid, i);
                if (half == 0) {
                    float4 v0 = E4[(size_t)ta * 32 + l];
                    a0.x += v0.x; a0.y += v0.y; a0.z += v0.z; a0.w += v0.w;
                }
            }
        }
        float4 t;
        t.x = (a0.x + a1.x) + (a2.x + a3.x);
        t.y = (a0.y + a1.y) + (a2.y + a3.y);
        t.z = (a0.z + a1.z) + (a2.z + a3.z);
        t.w = (a0.w + a1.w) + (a2.w + a3.w);
        t.x += __shfl_xor(t.x, 32);
        t.y += __shfl_xor(t.y, 32);
        t.z += __shfl_xor(t.z, 32);
        t.w += __shfl_xor(t.w, 32);
        if (half == 0) ((float4*)&hs[wid][IN_DIM])[l] = t;   // aggE -> cols 128..255
    }
    __syncthreads();
    // GEMM: 256 threads, 2 nodes per thread-group of 128
    int col = tid & 127, g = tid >> 7;          // g = 0,1 -> nodes 2g, 2g+1
    int m0 = 2 * g, m1 = 2 * g + 1;
    float acc0 = 0.f, acc1 = 0.f;
    for (int k = 0; k < TWO_IN; ++k) {
        float w = W1eff[k * IN_DIM + col];
        acc0 += hs[m0][k] * w;
        acc1 += hs[m1][k] * w;
    }
    float w256 = W1eff[(size_t)TWO_IN * IN_DIM + col];
    int v0 = blockIdx.x * 4 + m0;
    int v1 = blockIdx.x * 4 + m1;
    if (v0 < n) P[(size_t)v0 * IN_DIM + col] = __float2half(acc0 + degs[m0] * w256);
    if (v1 < n) P[(size_t)v1 * IN_DIM + col] = __float2half(acc1 + degs[m1] * w256);
}

// ---------- K_out: acc = P[v] + sum_in P[src]; out = relu(acc+b1) @ W2 + b2 ----------
__global__ void __launch_bounds__(512)
k_out(const __half* __restrict__ P, const int2* __restrict__ slots,
      const int* __restrict__ cnt,
      const float* __restrict__ b1, const float* __restrict__ W2,
      const float* __restrict__ b2,
      float* __restrict__ out, int n) {
    __shared__ float hs[ONB][IN_DIM];
    __shared__ float sb1v[IN_DIM];
    int tid = threadIdx.x;           // 512 (8 waves)
    int wid = tid >> 6, lane = tid & 63;
    int half = lane >> 5, l = lane & 31;
    int base = blockIdx.x * ONB;
    if (tid < IN_DIM) sb1v[tid] = b1[tid];
    const uint2* P8 = (const uint2*)P;   // row = 32 uint2 (8B = 4 halves)
    #pragma unroll
    for (int j = 0; j < 2; ++j) {
        int m = wid * 2 + j;
        int v = base + m;
        float4 r = {0.f, 0.f, 0.f, 0.f};
        if (v < n) {
            int c = cnt[v];
            size_t rb = (size_t)v * CAP;
            float4 a0 = {0,0,0,0}, a1 = {0,0,0,0}, a2 = {0,0,0,0}, a3 = {0,0,0,0};
            for (int b = 0; b < c; b += 64) {
                int rem = min(64, c - b);
                int sid = (b + lane < c) ? slots[rb + b + lane].x : 0;
                int i = 0;
                for (; i + 7 < rem; i += 8) {
                    int t0 = __builtin_amdgcn_readlane(sid, i + 0);
                    int t1 = __builtin_amdgcn_readlane(sid, i + 1);
                    int t2 = __builtin_amdgcn_readlane(sid, i + 2);
                    int t3 = __builtin_amdgcn_readlane(sid, i + 3);
                    int t4 = __builtin_amdgcn_readlane(sid, i + 4);
                    int t5 = __builtin_amdgcn_readlane(sid, i + 5);
                    int t6 = __builtin_amdgcn_readlane(sid, i + 6);
                    int t7 = __builtin_amdgcn_readlane(sid, i + 7);
                    int s0 = half ? t1 : t0;
                    int s1 = half ? t3 : t2;
                    int s2 = half ? t5 : t4;
                    int s3 = half ? t7 : t6;
                    uint2 u0 = P8[(size_t)s0 * 32 + l];
                    uint2 u1 = P8[(size_t)s1 * 32 + l];
                    uint2 u2 = P8[(size_t)s2 * 32 + l];
                    uint2 u3 = P8[(size_t)s3 * 32 + l];
                    float2 lo, hi;
                    lo = __half22float2(*(const __half2*)&u0.x);
                    hi = __half22float2(*(const __half2*)&u0.y);
                    a0.x += lo.x; a0.y += lo.y; a0.z += hi.x; a0.w += hi.y;
                    lo = __half22float2(*(const __half2*)&u1.x);
                    hi = __half22float2(*(const __half2*)&u1.y);
                    a1.x += lo.x; a1.y += lo.y; a1.z += hi.x; a1.w += hi.y;
                    lo = __half22float2(*(const __half2*)&u2.x);
                    hi = __half22float2(*(const __half2*)&u2.y);
                    a2.x += lo.x; a2.y += lo.y; a2.z += hi.x; a2.w += hi.y;
                    lo = __half22float2(*(const __half2*)&u3.x);
                    hi = __half22float2(*(const __half2*)&u3.y);
                    a3.x += lo.x; a3.y += lo.y; a3.z += hi.x; a3.w += hi.y;
                }
                for (; i + 1 < rem; i += 2) {
                    int ta = __builtin_amdgcn_readlane(sid, i);
                    int tb = __builtin_amdgcn_readlane(sid, i + 1);
                    int s0 = half ? tb : ta;
                    uint2 u0 = P8[(size_t)s0 * 32 + l];
                    float2 lo = __half22float2(*(const __half2*)&u0.x);
                    float2 hi = __half22float2(*(const __half2*)&u0.y);
                    a0.x += lo.x; a0.y += lo.y; a0.z += hi.x; a0.w += hi.y;
                }
                if (i < rem) {
                    int ta = __builtin_amdgcn_readlane(sid, i);
                    if (half == 0) {
                        uint2 u0 = P8[(size_t)ta * 32 + l];
                        float2 lo = __half22float2(*(const __half2*)&u0.x);
                        float2 hi = __half22float2(*(const __half2*)&u0.y);
                        a0.x += lo.x; a0.y += lo.y; a0.z += hi.x; a0.w += hi.y;
                    }
                }
            }
            if (half == 0) {   // self term, once
                uint2 u0 = P8[(size_t)v * 32 + l];
                float2 lo = __half22float2(*(const __half2*)&u0.x);
                float2 hi = __half22float2(*(const __half2*)&u0.y);
                a0.x += lo.x; a0.y += lo.y; a0.z += hi.x; a0.w += hi.y;
            }
            r.x = (a0.x + a1.x) + (a2.x + a3.x);
            r.y = (a0.y + a1.y) + (a2.y + a3.y);
            r.z = (a0.z + a1.z) + (a2.z + a3.z);
            r.w = (a0.w + a1.w) + (a2.w + a3.w);
            r.x += __shfl_xor(r.x, 32);
            r.y += __shfl_xor(r.y, 32);
            r.z += __shfl_xor(r.z, 32);
            r.w += __shfl_xor(r.w, 32);
        }
        if (half == 0 && v < n) ((float4*)&hs[m][0])[l] = r;
    }
    __syncthreads();
    int col = tid & 127, grp = tid >> 7;     // grp = 0..3
    float acc[4] = {0.f, 0.f, 0.f, 0.f};
    for (int k = 0; k < IN_DIM; ++k) {
        float w = W2[k * IN_DIM + col];
        float bb = sb1v[k];
        #pragma unroll
        for (int j = 0; j < 4; ++j) {
            float t = hs[grp + 4 * j][k] + bb;
            acc[j] += (t > 0.f ? t : 0.f) * w;
        }
    }
    float b2v = b2[col];
    #pragma unroll
    for (int j = 0; j < 4; ++j) {
        int v = base + grp + 4 * j;
        if (v < n) out[(size_t)v * IN_DIM + col] = acc[j] + b2v;
    }
}

extern "C" void kernel_launch(void* const* d_in, const int* in_sizes, int n_in,
                              void* d_out, int out_size, void* d_ws, size_t ws_size,
                              hipStream_t stream) {
    const float* x         = (const float*)d_in[0];
    const int*   ei        = (const int*)d_in[1];
    const float* edge_attr = (const float*)d_in[2];
    const float* We        = (const float*)d_in[3];
    const float* be        = (const float*)d_in[4];
    const float* W1        = (const float*)d_in[5];
    const float* b1        = (const float*)d_in[6];
    const float* W2        = (const float*)d_in[7];
    const float* b2        = (const float*)d_in[8];
    float* out = (float*)d_out;

    int N = in_sizes[0] / IN_DIM;
    int E = in_sizes[1] / 2;
    const int* src = ei;
    const int* dst = ei + E;

    char* ws = (char*)d_ws;
    size_t o = 0;
    auto take = [&](size_t nbytes) -> void* {
        void* p = (void*)(ws + o);
        o += (nbytes + 255) & ~(size_t)255;
        return p;
    };
    int*    cnt   = (int*)take((size_t)N * 4);
    int2*   slots = (int2*)take(((size_t)N * CAP + 64) * 8);
    __half* P     = (__half*)take((size_t)N * IN_DIM * 2);
    float*  W1eff = (float*)take((size_t)(TWO_IN + 1) * IN_DIM * 4);
    (void)ws_size; (void)n_in; (void)out_size;

    int gE = (E + 255) / 256;
    int gA = (N + 3) / 4;                // 4 nodes (waves) per block
    int gO = (N + ONB - 1) / ONB;

    k_prep<<<16, 128, 0, stream>>>(We, be, W1, W1eff, cnt, N);
    k_fill<<<gE, 256, 0, stream>>>(src, dst, cnt, slots, E);
    k_aggP<<<gA, 256, 0, stream>>>(x, edge_attr, slots, cnt, W1eff, P, N);
    k_out<<<gO, 512, 0, stream>>>(P, slots, cnt, b1, W2, b2, out, N);
}